// Round 4
// baseline (211.373 us; speedup 1.0000x reference)
//
#include <hip/hip_runtime.h>
#include <hip/hip_bf16.h>
#include <math.h>

typedef __bf16 bf16x8 __attribute__((ext_vector_type(8)));
typedef float f32x4 __attribute__((ext_vector_type(4)));

#define T_TOK 2048
#define HD 1024
#define ID 768
#define NE 16
#define NEZ 24
#define NK 4
#define SCALE_F 2.5f

#define MFMA(a, b, c) __builtin_amdgcn_mfma_f32_16x16x32_bf16(a, b, c, 0, 0, 0)

__device__ __forceinline__ unsigned short f2bf(float f) {
  unsigned int u = __builtin_bit_cast(unsigned int, f);
  u += 0x7FFFu + ((u >> 16) & 1u);          // RNE
  return (unsigned short)(u >> 16);
}

// native casts -> v_cvt_pk_bf16_f32
__device__ __forceinline__ bf16x8 cvt8(float4 a, float4 b) {
  bf16x8 t;
  t[0] = (__bf16)a.x; t[1] = (__bf16)a.y; t[2] = (__bf16)a.z; t[3] = (__bf16)a.w;
  t[4] = (__bf16)b.x; t[5] = (__bf16)b.y; t[6] = (__bf16)b.z; t[7] = (__bf16)b.w;
  return t;
}

// async global->LDS, 16B per lane; dest linear (base + lane*16)
__device__ __forceinline__ void gload16(const void* g, void* l) {
  __builtin_amdgcn_global_load_lds(
      (const __attribute__((address_space(1))) void*)(unsigned long long)(uintptr_t)g,
      (__attribute__((address_space(3))) void*)(uintptr_t)l, 16, 0, 0);
}

// ---------------- router + fused build --------------------------------------
// 256 thr = 4 waves; each wave owns 2 tokens. Coalesced float4 w reads shared
// across both tokens; butterfly-shfl logit reduce; replicated top-4 from LDS.
__global__ __launch_bounds__(256) void router_k(
    const float* __restrict__ x, const float* __restrict__ wr,
    const float* __restrict__ bias,
    int* __restrict__ counts, int* __restrict__ lists, float* __restrict__ wlist,
    unsigned short* __restrict__ xb, float* __restrict__ out) {
  const int wv = threadIdx.x >> 6, l = threadIdx.x & 63;
  const int t0 = (blockIdx.x * 4 + wv) * 2;
  __shared__ float s_sc[4][2][NEZ];
  __shared__ float s_scb[4][2][NEZ];

  float4 x0[4], x1[4];
#pragma unroll
  for (int c = 0; c < 4; ++c) {
    x0[c] = *(const float4*)(x + (size_t)t0 * HD + c * 256 + l * 4);
    x1[c] = *(const float4*)(x + (size_t)(t0 + 1) * HD + c * 256 + l * 4);
  }
#pragma unroll
  for (int c = 0; c < 4; ++c) {
    ushort4 h0, h1;
    h0.x = f2bf(x0[c].x); h0.y = f2bf(x0[c].y); h0.z = f2bf(x0[c].z); h0.w = f2bf(x0[c].w);
    h1.x = f2bf(x1[c].x); h1.y = f2bf(x1[c].y); h1.z = f2bf(x1[c].z); h1.w = f2bf(x1[c].w);
    *(ushort4*)(xb + (size_t)t0 * HD + c * 256 + l * 4) = h0;
    *(ushort4*)(xb + (size_t)(t0 + 1) * HD + c * 256 + l * 4) = h1;
  }
#pragma unroll
  for (int e = 0; e < NEZ; ++e) {
    float4 a0 = {0.f, 0.f, 0.f, 0.f}, a1 = {0.f, 0.f, 0.f, 0.f};
#pragma unroll
    for (int c = 0; c < 4; ++c) {
      float4 w4 = *(const float4*)(wr + (size_t)e * HD + c * 256 + l * 4);
      a0.x = fmaf(w4.x, x0[c].x, a0.x); a0.y = fmaf(w4.y, x0[c].y, a0.y);
      a0.z = fmaf(w4.z, x0[c].z, a0.z); a0.w = fmaf(w4.w, x0[c].w, a0.w);
      a1.x = fmaf(w4.x, x1[c].x, a1.x); a1.y = fmaf(w4.y, x1[c].y, a1.y);
      a1.z = fmaf(w4.z, x1[c].z, a1.z); a1.w = fmaf(w4.w, x1[c].w, a1.w);
    }
    float r0 = (a0.x + a0.y) + (a0.z + a0.w);
    float r1 = (a1.x + a1.y) + (a1.z + a1.w);
#pragma unroll
    for (int s = 1; s < 64; s <<= 1) {
      r0 += __shfl_xor(r0, s);
      r1 += __shfl_xor(r1, s);
    }
    if (l == 0) {
      float be = bias[e];
      float s0 = 1.f / (1.f + expf(-r0)), s1 = 1.f / (1.f + expf(-r1));
      s_sc[wv][0][e] = s0; s_scb[wv][0][e] = s0 + be;
      s_sc[wv][1][e] = s1; s_scb[wv][1][e] = s1 + be;
    }
  }
  // per-token top-4 (replicated across lanes; lane 0 does the atomics)
  float zw[2];
#pragma unroll
  for (int tk = 0; tk < 2; ++tk) {
    const float* sc = s_sc[wv][tk];
    const float* scb = s_scb[wv][tk];
    unsigned picked = 0; int ids[NK]; float wvv[NK]; float ssum = 0.f;
#pragma unroll
    for (int k = 0; k < NK; ++k) {
      int best = 0; float bv = -1e30f;
      for (int e = 0; e < NEZ; ++e) {
        float v = scb[e];
        bool take = (((picked >> e) & 1u) == 0) && (v > bv);
        best = take ? e : best; bv = take ? v : bv;
      }
      picked |= 1u << best;
      ids[k] = best; wvv[k] = sc[best]; ssum += sc[best];
    }
    float zz = 0.f;
    const float inv = SCALE_F / ssum;
    const int t = t0 + tk;
#pragma unroll
    for (int k = 0; k < NK; ++k) {
      float w = wvv[k] * inv;
      if (ids[k] >= NE) {
        zz += w;
      } else if (l == 0) {
        int p = atomicAdd(&counts[ids[k]], 1);
        lists[ids[k] * T_TOK + p] = t;
        wlist[ids[k] * T_TOK + p] = w;
      }
    }
    zw[tk] = zz;
  }
#pragma unroll
  for (int c = 0; c < 4; ++c) {
    float4 o0, o1;
    o0.x = x0[c].x * zw[0]; o0.y = x0[c].y * zw[0];
    o0.z = x0[c].z * zw[0]; o0.w = x0[c].w * zw[0];
    o1.x = x1[c].x * zw[1]; o1.y = x1[c].y * zw[1];
    o1.z = x1[c].z * zw[1]; o1.w = x1[c].w * zw[1];
    *(float4*)(out + (size_t)t0 * HD + c * 256 + l * 4) = o0;
    *(float4*)(out + (size_t)(t0 + 1) * HD + c * 256 + l * 4) = o1;
  }
}

__global__ void scan_k(const int* __restrict__ counts, int* __restrict__ offs) {
  if (threadIdx.x == 0 && blockIdx.x == 0) {
    int s = 0;
    for (int e = 0; e < NE; ++e) { offs[e] = s; s += counts[e]; }
    offs[NE] = s;
  }
}

// ============================ gate/up GEMM =================================
// 256 thr / 4 waves (2M x 2N). Tile 128M x 64N(g,u) x 32K, double-buffered.
// LDS/buf: A [128][32]bf16 (64B pitch, slot=(c+(row>>1))&3),
//          G,U [64][32]f32 (128B pitch, slot=(c+row)&7). 2x24KB.
__global__ __launch_bounds__(256, 3) void gu_k(
    const unsigned short* __restrict__ xb,
    const float* __restrict__ wg, const float* __restrict__ wu,
    const int* __restrict__ counts, const int* __restrict__ offs,
    const int* __restrict__ lists, unsigned short* __restrict__ abuf) {
  const int e = blockIdx.z;
  const int cnt = counts[e];
  const int m0 = blockIdx.y * 128;
  if (m0 >= cnt) return;
  const int n0 = blockIdx.x * 64;

  __shared__ int toks[128];
  __shared__ char lds[2][24576];

  const int tid = threadIdx.x;
  if (tid < 128) {
    int m = m0 + tid;
    toks[tid] = (m < cnt) ? lists[e * T_TOK + m] : 0;
  }
  __syncthreads();

  // A: unit u=j*256+tid -> row=j*64+(tid>>2), slot p=tid&3, chunk c=(p-(row>>1))&3
  const unsigned short* asrc[2];
#pragma unroll
  for (int j = 0; j < 2; ++j) {
    int row = j * 64 + (tid >> 2);
    int c = ((tid & 3) - (row >> 1)) & 3;
    asrc[j] = xb + (size_t)toks[row] * HD + c * 8;
  }
  // B: unit u=j*256+tid -> row=j*32+(tid>>3), slot p=tid&7, chunk c=(p-row)&7
  const size_t wbase = (size_t)e * ID * HD;
  const float* gsrc[2]; const float* usrc[2];
#pragma unroll
  for (int j = 0; j < 2; ++j) {
    int row = j * 32 + (tid >> 3);
    int c = ((tid & 7) - row) & 7;
    size_t ro = wbase + (size_t)(n0 + row) * HD + c * 4;
    gsrc[j] = wg + ro; usrc[j] = wu + ro;
  }

  const int wid = tid >> 6, l = tid & 63;
  const int wm = (wid >> 1) * 64, wn = (wid & 1) * 32;
  const int q = l >> 4, r = l & 15;

  f32x4 ag[4][2] = {}; f32x4 au[4][2] = {};

  auto stage = [&](int b, int k0) {
    char* dst = &lds[b][0] + tid * 16;
#pragma unroll
    for (int j = 0; j < 2; ++j) {
      gload16(asrc[j] + k0, dst + j * 4096);
      gload16(gsrc[j] + k0, dst + 8192 + j * 4096);
      gload16(usrc[j] + k0, dst + 16384 + j * 4096);
    }
  };
  auto comp = [&](int b) {
    const char* base = &lds[b][0];
    bf16x8 a[4];
#pragma unroll
    for (int fm = 0; fm < 4; ++fm) {
      int rr = wm + fm * 16 + r;
      int p = (q + (rr >> 1)) & 3;
      a[fm] = *(const bf16x8*)(base + rr * 64 + p * 16);
    }
#pragma unroll
    for (int fn = 0; fn < 2; ++fn) {
      int cc = wn + fn * 16 + r;
      int p0 = (2 * q + cc) & 7, p1 = (2 * q + 1 + cc) & 7;
      const char* pg = base + 8192 + cc * 128;
      const char* pu = base + 16384 + cc * 128;
      float4 g0 = *(const float4*)(pg + p0 * 16);
      float4 g1 = *(const float4*)(pg + p1 * 16);
      float4 u0 = *(const float4*)(pu + p0 * 16);
      float4 u1 = *(const float4*)(pu + p1 * 16);
      bf16x8 bg = cvt8(g0, g1), bu = cvt8(u0, u1);
#pragma unroll
      for (int fm = 0; fm < 4; ++fm) {
        ag[fm][fn] = MFMA(a[fm], bg, ag[fm][fn]);
        au[fm][fn] = MFMA(a[fm], bu, au[fm][fn]);
      }
    }
  };

  stage(0, 0);
  __syncthreads();
  for (int t = 0; t < 32; t += 2) {
    stage(1, (t + 1) * 32);    // next tile in flight during compute
    comp(0);
    __syncthreads();
    if (t + 2 < 32) stage(0, (t + 2) * 32);
    comp(1);
    __syncthreads();
  }

  const int rowbase = offs[e] + m0;
#pragma unroll
  for (int fm = 0; fm < 4; ++fm)
#pragma unroll
    for (int fn = 0; fn < 2; ++fn)
#pragma unroll
      for (int i2 = 0; i2 < 4; ++i2) {
        int mr = wm + fm * 16 + q * 4 + i2;       // D: row=(l>>4)*4+reg
        if (m0 + mr < cnt) {
          float g = ag[fm][fn][i2], u = au[fm][fn][i2];
          float s = 1.0f / (1.0f + expf(-g));
          float aa = g * s * u;                   // silu(g)*u
          int col = n0 + wn + fn * 16 + r;        // D: col=l&15
          abuf[(size_t)(rowbase + mr) * ID + col] = f2bf(aa);
        }
      }
}

// ============================ down GEMM ====================================
// Tile 128M x 128N x 32K, double-buffered. A [128][32]bf16, B [128][32]f32.
__global__ __launch_bounds__(256, 3) void dn_k(
    const unsigned short* __restrict__ abuf,
    const float* __restrict__ wd,
    const int* __restrict__ counts, const int* __restrict__ offs,
    const int* __restrict__ lists, const float* __restrict__ wlist,
    float* __restrict__ out) {
  const int e = blockIdx.z;
  const int cnt = counts[e];
  const int m0 = blockIdx.y * 128;
  if (m0 >= cnt) return;
  const int n0 = blockIdx.x * 128;

  __shared__ int toks[128];
  __shared__ float wts[128];
  __shared__ char lds[2][24576];

  const int tid = threadIdx.x;
  if (tid < 128) {
    int m = m0 + tid;
    if (m < cnt) { toks[tid] = lists[e * T_TOK + m]; wts[tid] = wlist[e * T_TOK + m]; }
    else         { toks[tid] = 0;                    wts[tid] = 0.f; }
  }
  __syncthreads();

  const int rowbase = offs[e] + m0;
  const unsigned short* asrc[2];
#pragma unroll
  for (int j = 0; j < 2; ++j) {
    int row = j * 64 + (tid >> 2);
    int c = ((tid & 3) - (row >> 1)) & 3;
    int grow = (m0 + row < cnt) ? rowbase + row : rowbase;   // clamp to valid
    asrc[j] = abuf + (size_t)grow * ID + c * 8;
  }
  const float* bsrc[4];
#pragma unroll
  for (int j = 0; j < 4; ++j) {
    int row = j * 32 + (tid >> 3);
    int c = ((tid & 7) - row) & 7;
    bsrc[j] = wd + (size_t)e * HD * ID + (size_t)(n0 + row) * ID + c * 4;
  }

  const int wid = tid >> 6, l = tid & 63;
  const int wm = (wid >> 1) * 64, wn = (wid & 1) * 64;
  const int q = l >> 4, r = l & 15;

  f32x4 acc[4][4] = {};

  auto stage = [&](int b, int k0) {
    char* dst = &lds[b][0] + tid * 16;
#pragma unroll
    for (int j = 0; j < 2; ++j) gload16(asrc[j] + k0, dst + j * 4096);
#pragma unroll
    for (int j = 0; j < 4; ++j) gload16(bsrc[j] + k0, dst + 8192 + j * 4096);
  };
  auto comp = [&](int b) {
    const char* base = &lds[b][0];
    bf16x8 a[4];
#pragma unroll
    for (int fm = 0; fm < 4; ++fm) {
      int rr = wm + fm * 16 + r;
      int p = (q + (rr >> 1)) & 3;
      a[fm] = *(const bf16x8*)(base + rr * 64 + p * 16);
    }
#pragma unroll
    for (int fn = 0; fn < 4; ++fn) {
      int cc = wn + fn * 16 + r;
      int p0 = (2 * q + cc) & 7, p1 = (2 * q + 1 + cc) & 7;
      const char* pb = base + 8192 + cc * 128;
      float4 b0 = *(const float4*)(pb + p0 * 16);
      float4 b1 = *(const float4*)(pb + p1 * 16);
      bf16x8 bb = cvt8(b0, b1);
#pragma unroll
      for (int fm = 0; fm < 4; ++fm)
        acc[fm][fn] = MFMA(a[fm], bb, acc[fm][fn]);
    }
  };

  stage(0, 0);
  __syncthreads();
  for (int t = 0; t < 24; t += 2) {
    stage(1, (t + 1) * 32);
    comp(0);
    __syncthreads();
    if (t + 2 < 24) stage(0, (t + 2) * 32);
    comp(1);
    __syncthreads();
  }

#pragma unroll
  for (int fm = 0; fm < 4; ++fm)
#pragma unroll
    for (int fn = 0; fn < 4; ++fn)
#pragma unroll
      for (int i2 = 0; i2 < 4; ++i2) {
        int mr = wm + fm * 16 + q * 4 + i2;
        if (m0 + mr < cnt) {
          int col = n0 + wn + fn * 16 + r;
          atomicAdd(&out[(size_t)toks[mr] * HD + col], acc[fm][fn][i2] * wts[mr]);
        }
      }
}

extern "C" void kernel_launch(void* const* d_in, const int* in_sizes, int n_in,
                              void* d_out, int out_size, void* d_ws, size_t ws_size,
                              hipStream_t stream) {
  (void)in_sizes; (void)n_in; (void)out_size; (void)ws_size;
  const float* x    = (const float*)d_in[0];
  const float* wr   = (const float*)d_in[3];
  const float* bias = (const float*)d_in[4];
  const float* wg   = (const float*)d_in[5];
  const float* wu   = (const float*)d_in[6];
  const float* wd   = (const float*)d_in[7];
  float* out = (float*)d_out;

  char* p = (char*)d_ws;
  auto alloc = [&](size_t bytes) {
    char* r = p;
    p += (bytes + 255) & ~(size_t)255;
    return r;
  };
  int*   counts  = (int*)alloc(NE * 4);
  int*   offs    = (int*)alloc((NE + 1) * 4);
  int*   lists   = (int*)alloc((size_t)NE * T_TOK * 4);
  float* wlist   = (float*)alloc((size_t)NE * T_TOK * 4);
  unsigned short* xb   = (unsigned short*)alloc((size_t)T_TOK * HD * 2);
  unsigned short* abuf = (unsigned short*)alloc((size_t)(T_TOK * NK + 128) * ID * 2);

  hipMemsetAsync(counts, 0, NE * 4, stream);
  router_k<<<T_TOK / 8, 256, 0, stream>>>(x, wr, bias, counts, lists, wlist, xb, out);
  scan_k<<<1, 64, 0, stream>>>(counts, offs);
  gu_k<<<dim3(ID / 64, T_TOK / 128, NE), 256, 0, stream>>>(xb, wg, wu, counts, offs, lists, abuf);
  dn_k<<<dim3(HD / 128, T_TOK / 128, NE), 256, 0, stream>>>(abuf, wd, counts, offs, lists, wlist, out);
}

// Round 5
// 128.697 us; speedup vs baseline: 1.6424x; 1.6424x over previous
//
#include <hip/hip_runtime.h>
#include <hip/hip_bf16.h>
#include <math.h>

typedef __bf16 bf16x8 __attribute__((ext_vector_type(8)));
typedef float f32x4 __attribute__((ext_vector_type(4)));

#define T_TOK 2048
#define HD 1024
#define ID 768
#define NE 16
#define NEZ 24
#define NK 4
#define SCALE_F 2.5f

#define MFMA(a, b, c) __builtin_amdgcn_mfma_f32_16x16x32_bf16(a, b, c, 0, 0, 0)

__device__ __forceinline__ unsigned short f2bf(float f) {
  unsigned int u = __builtin_bit_cast(unsigned int, f);
  u += 0x7FFFu + ((u >> 16) & 1u);          // RNE
  return (unsigned short)(u >> 16);
}

// native casts -> v_cvt_pk_bf16_f32
__device__ __forceinline__ bf16x8 cvt8(float4 a, float4 b) {
  bf16x8 t;
  t[0] = (__bf16)a.x; t[1] = (__bf16)a.y; t[2] = (__bf16)a.z; t[3] = (__bf16)a.w;
  t[4] = (__bf16)b.x; t[5] = (__bf16)b.y; t[6] = (__bf16)b.z; t[7] = (__bf16)b.w;
  return t;
}

// async global->LDS, 16B per lane; dest linear (base + lane*16)
__device__ __forceinline__ void gload16(const void* g, void* l) {
  __builtin_amdgcn_global_load_lds(
      (const __attribute__((address_space(1))) void*)(unsigned long long)(uintptr_t)g,
      (__attribute__((address_space(3))) void*)(uintptr_t)l, 16, 0, 0);
}

// ---------------- router v3: wave-per-token, register-only ------------------
// 512 blocks x 256 thr; wave w owns token t = blockIdx.x*4+w.
// Batched weight loads (unroll 4), deferred level-batched butterfly reduce,
// register-resident top-4 (no LDS), lanes 0..3 do the list atomics.
__global__ __launch_bounds__(256) void router_k(
    const float* __restrict__ x, const float* __restrict__ wr,
    const float* __restrict__ bias,
    int* __restrict__ counts, int* __restrict__ lists, float* __restrict__ wlist,
    unsigned short* __restrict__ xb, float* __restrict__ out) {
  const int wave = threadIdx.x >> 6, l = threadIdx.x & 63;
  const int t = blockIdx.x * 4 + wave;

  float4 xr[4];
#pragma unroll
  for (int c = 0; c < 4; ++c)
    xr[c] = *(const float4*)(x + (size_t)t * HD + c * 256 + l * 4);
#pragma unroll
  for (int c = 0; c < 4; ++c) {
    ushort4 h;
    h.x = f2bf(xr[c].x); h.y = f2bf(xr[c].y); h.z = f2bf(xr[c].z); h.w = f2bf(xr[c].w);
    *(ushort4*)(xb + (size_t)t * HD + c * 256 + l * 4) = h;
  }

  float acc[NEZ];
#pragma unroll 4
  for (int e = 0; e < NEZ; ++e) {
    float4 s = {0.f, 0.f, 0.f, 0.f};
#pragma unroll
    for (int c = 0; c < 4; ++c) {
      float4 w4 = *(const float4*)(wr + (size_t)e * HD + c * 256 + l * 4);
      s.x = fmaf(w4.x, xr[c].x, s.x); s.y = fmaf(w4.y, xr[c].y, s.y);
      s.z = fmaf(w4.z, xr[c].z, s.z); s.w = fmaf(w4.w, xr[c].w, s.w);
    }
    acc[e] = (s.x + s.y) + (s.z + s.w);
  }
  // level-batched butterfly: 24 independent shfls per level, 6 levels
#pragma unroll
  for (int s = 1; s < 64; s <<= 1) {
#pragma unroll
    for (int e = 0; e < NEZ; ++e) acc[e] += __shfl_xor(acc[e], s);
  }
  // sigmoid + bias (replicated on all lanes; registers only)
  float sc[NEZ], scb[NEZ];
#pragma unroll
  for (int e = 0; e < NEZ; ++e) {
    float s = 1.f / (1.f + expf(-acc[e]));
    sc[e] = s;
    scb[e] = s + bias[e];
  }
  // top-4, fully unrolled (static indices; value tracked with argmax)
  unsigned picked = 0;
  int ids[NK]; float wv[NK]; float ssum = 0.f;
#pragma unroll
  for (int k = 0; k < NK; ++k) {
    int best = 0; float bv = -1e30f; float bsc = 0.f;
#pragma unroll
    for (int e = 0; e < NEZ; ++e) {
      bool take = (((picked >> e) & 1u) == 0) && (scb[e] > bv);
      best = take ? e : best;
      bv = take ? scb[e] : bv;
      bsc = take ? sc[e] : bsc;
    }
    picked |= 1u << best;
    ids[k] = best; wv[k] = bsc; ssum += bsc;
  }
  const float inv = SCALE_F / ssum;
  float zw = 0.f;
#pragma unroll
  for (int k = 0; k < NK; ++k)
    zw += (ids[k] >= NE) ? wv[k] * inv : 0.f;
  // lanes 0..3: one routed pick each (single divergent atomic instr)
  if (l < NK) {
    int id = ids[l];
    if (id < NE) {
      int p = atomicAdd(&counts[id], 1);
      lists[id * T_TOK + p] = t;
      wlist[id * T_TOK + p] = wv[l] * inv;
    }
  }
#pragma unroll
  for (int c = 0; c < 4; ++c) {
    float4 o;
    o.x = xr[c].x * zw; o.y = xr[c].y * zw;
    o.z = xr[c].z * zw; o.w = xr[c].w * zw;
    *(float4*)(out + (size_t)t * HD + c * 256 + l * 4) = o;
  }
}

__global__ void scan_k(const int* __restrict__ counts, int* __restrict__ offs) {
  if (threadIdx.x == 0 && blockIdx.x == 0) {
    int s = 0;
    for (int e = 0; e < NE; ++e) { offs[e] = s; s += counts[e]; }
    offs[NE] = s;
  }
}

// ============================ gate/up GEMM =================================
// 1D grid 3072 = 8 XCD chunks x 384; logical order y(16) fastest, x(12), e(16)
// so the 3 live y-blocks sharing a B-tile run consecutively on one XCD.
// Tile 128M x 64N(g,u) x 32K, double-buffered (2x24KB LDS).
__global__ __launch_bounds__(256, 3) void gu_k(
    const unsigned short* __restrict__ xb,
    const float* __restrict__ wg, const float* __restrict__ wu,
    const int* __restrict__ counts, const int* __restrict__ offs,
    const int* __restrict__ lists, unsigned short* __restrict__ abuf) {
  const int b = blockIdx.x;
  const int L = (b & 7) * 384 + (b >> 3);   // XCD-contiguous logical id
  const int e = L / 192;
  const int rem = L % 192;
  const int xs = rem / 16, ys = rem % 16;
  const int cnt = counts[e];
  const int m0 = ys * 128;
  if (m0 >= cnt) return;
  const int n0 = xs * 64;

  __shared__ int toks[128];
  __shared__ char lds[2][24576];

  const int tid = threadIdx.x;
  if (tid < 128) {
    int m = m0 + tid;
    toks[tid] = (m < cnt) ? lists[e * T_TOK + m] : 0;
  }
  __syncthreads();

  // A: unit u=j*256+tid -> row=j*64+(tid>>2), slot p=tid&3, chunk c=(p-(row>>1))&3
  const unsigned short* asrc[2];
#pragma unroll
  for (int j = 0; j < 2; ++j) {
    int row = j * 64 + (tid >> 2);
    int c = ((tid & 3) - (row >> 1)) & 3;
    asrc[j] = xb + (size_t)toks[row] * HD + c * 8;
  }
  // B: unit u=j*256+tid -> row=j*32+(tid>>3), slot p=tid&7, chunk c=(p-row)&7
  const size_t wbase = (size_t)e * ID * HD;
  const float* gsrc[2]; const float* usrc[2];
#pragma unroll
  for (int j = 0; j < 2; ++j) {
    int row = j * 32 + (tid >> 3);
    int c = ((tid & 7) - row) & 7;
    size_t ro = wbase + (size_t)(n0 + row) * HD + c * 4;
    gsrc[j] = wg + ro; usrc[j] = wu + ro;
  }

  const int wid = tid >> 6, l = tid & 63;
  const int wm = (wid >> 1) * 64, wn = (wid & 1) * 32;
  const int q = l >> 4, r = l & 15;

  f32x4 ag[4][2] = {}; f32x4 au[4][2] = {};

  auto stage = [&](int bb, int k0) {
    char* dst = &lds[bb][0] + tid * 16;
#pragma unroll
    for (int j = 0; j < 2; ++j) {
      gload16(asrc[j] + k0, dst + j * 4096);
      gload16(gsrc[j] + k0, dst + 8192 + j * 4096);
      gload16(usrc[j] + k0, dst + 16384 + j * 4096);
    }
  };
  auto comp = [&](int bb) {
    const char* base = &lds[bb][0];
    bf16x8 a[4];
#pragma unroll
    for (int fm = 0; fm < 4; ++fm) {
      int rr = wm + fm * 16 + r;
      int p = (q + (rr >> 1)) & 3;
      a[fm] = *(const bf16x8*)(base + rr * 64 + p * 16);
    }
#pragma unroll
    for (int fn = 0; fn < 2; ++fn) {
      int cc = wn + fn * 16 + r;
      int p0 = (2 * q + cc) & 7, p1 = (2 * q + 1 + cc) & 7;
      const char* pg = base + 8192 + cc * 128;
      const char* pu = base + 16384 + cc * 128;
      float4 g0 = *(const float4*)(pg + p0 * 16);
      float4 g1 = *(const float4*)(pg + p1 * 16);
      float4 u0 = *(const float4*)(pu + p0 * 16);
      float4 u1 = *(const float4*)(pu + p1 * 16);
      bf16x8 bg = cvt8(g0, g1), bu = cvt8(u0, u1);
#pragma unroll
      for (int fm = 0; fm < 4; ++fm) {
        ag[fm][fn] = MFMA(a[fm], bg, ag[fm][fn]);
        au[fm][fn] = MFMA(a[fm], bu, au[fm][fn]);
      }
    }
  };

  stage(0, 0);
  __syncthreads();
  for (int t = 0; t < 32; t += 2) {
    stage(1, (t + 1) * 32);    // next tile in flight during compute
    comp(0);
    __syncthreads();
    if (t + 2 < 32) stage(0, (t + 2) * 32);
    comp(1);
    __syncthreads();
  }

  const int rowbase = offs[e] + m0;
#pragma unroll
  for (int fm = 0; fm < 4; ++fm)
#pragma unroll
    for (int fn = 0; fn < 2; ++fn)
#pragma unroll
      for (int i2 = 0; i2 < 4; ++i2) {
        int mr = wm + fm * 16 + q * 4 + i2;       // D: row=(l>>4)*4+reg
        if (m0 + mr < cnt) {
          float g = ag[fm][fn][i2], u = au[fm][fn][i2];
          float s = 1.0f / (1.0f + expf(-g));
          float aa = g * s * u;                   // silu(g)*u
          int col = n0 + wn + fn * 16 + r;        // D: col=l&15
          abuf[(size_t)(rowbase + mr) * ID + col] = f2bf(aa);
        }
      }
}

// ============================ down GEMM ====================================
// 1D grid 2048 = 8 x 256; logical order y(16), x(8), e(16).
// Tile 128M x 128N x 32K, double-buffered.
__global__ __launch_bounds__(256, 3) void dn_k(
    const unsigned short* __restrict__ abuf,
    const float* __restrict__ wd,
    const int* __restrict__ counts, const int* __restrict__ offs,
    const int* __restrict__ lists, const float* __restrict__ wlist,
    float* __restrict__ out) {
  const int b = blockIdx.x;
  const int L = (b & 7) * 256 + (b >> 3);
  const int e = L / 128;
  const int rem = L % 128;
  const int xs = rem / 16, ys = rem % 16;
  const int cnt = counts[e];
  const int m0 = ys * 128;
  if (m0 >= cnt) return;
  const int n0 = xs * 128;

  __shared__ int toks[128];
  __shared__ float wts[128];
  __shared__ char lds[2][24576];

  const int tid = threadIdx.x;
  if (tid < 128) {
    int m = m0 + tid;
    if (m < cnt) { toks[tid] = lists[e * T_TOK + m]; wts[tid] = wlist[e * T_TOK + m]; }
    else         { toks[tid] = 0;                    wts[tid] = 0.f; }
  }
  __syncthreads();

  const int rowbase = offs[e] + m0;
  const unsigned short* asrc[2];
#pragma unroll
  for (int j = 0; j < 2; ++j) {
    int row = j * 64 + (tid >> 2);
    int c = ((tid & 3) - (row >> 1)) & 3;
    int grow = (m0 + row < cnt) ? rowbase + row : rowbase;   // clamp to valid
    asrc[j] = abuf + (size_t)grow * ID + c * 8;
  }
  const float* bsrc[4];
#pragma unroll
  for (int j = 0; j < 4; ++j) {
    int row = j * 32 + (tid >> 3);
    int c = ((tid & 7) - row) & 7;
    bsrc[j] = wd + (size_t)e * HD * ID + (size_t)(n0 + row) * ID + c * 4;
  }

  const int wid = tid >> 6, l = tid & 63;
  const int wm = (wid >> 1) * 64, wn = (wid & 1) * 64;
  const int q = l >> 4, r = l & 15;

  f32x4 acc[4][4] = {};

  auto stage = [&](int bb, int k0) {
    char* dst = &lds[bb][0] + tid * 16;
#pragma unroll
    for (int j = 0; j < 2; ++j) gload16(asrc[j] + k0, dst + j * 4096);
#pragma unroll
    for (int j = 0; j < 4; ++j) gload16(bsrc[j] + k0, dst + 8192 + j * 4096);
  };
  auto comp = [&](int bb) {
    const char* base = &lds[bb][0];
    bf16x8 a[4];
#pragma unroll
    for (int fm = 0; fm < 4; ++fm) {
      int rr = wm + fm * 16 + r;
      int p = (q + (rr >> 1)) & 3;
      a[fm] = *(const bf16x8*)(base + rr * 64 + p * 16);
    }
#pragma unroll
    for (int fn = 0; fn < 4; ++fn) {
      int cc = wn + fn * 16 + r;
      int p0 = (2 * q + cc) & 7, p1 = (2 * q + 1 + cc) & 7;
      const char* pb = base + 8192 + cc * 128;
      float4 b0 = *(const float4*)(pb + p0 * 16);
      float4 b1 = *(const float4*)(pb + p1 * 16);
      bf16x8 bb2 = cvt8(b0, b1);
#pragma unroll
      for (int fm = 0; fm < 4; ++fm)
        acc[fm][fn] = MFMA(a[fm], bb2, acc[fm][fn]);
    }
  };

  stage(0, 0);
  __syncthreads();
  for (int t = 0; t < 24; t += 2) {
    stage(1, (t + 1) * 32);
    comp(0);
    __syncthreads();
    if (t + 2 < 24) stage(0, (t + 2) * 32);
    comp(1);
    __syncthreads();
  }

#pragma unroll
  for (int fm = 0; fm < 4; ++fm)
#pragma unroll
    for (int fn = 0; fn < 4; ++fn)
#pragma unroll
      for (int i2 = 0; i2 < 4; ++i2) {
        int mr = wm + fm * 16 + q * 4 + i2;
        if (m0 + mr < cnt) {
          int col = n0 + wn + fn * 16 + r;
          atomicAdd(&out[(size_t)toks[mr] * HD + col], acc[fm][fn][i2] * wts[mr]);
        }
      }
}

extern "C" void kernel_launch(void* const* d_in, const int* in_sizes, int n_in,
                              void* d_out, int out_size, void* d_ws, size_t ws_size,
                              hipStream_t stream) {
  (void)in_sizes; (void)n_in; (void)out_size; (void)ws_size;
  const float* x    = (const float*)d_in[0];
  const float* wr   = (const float*)d_in[3];
  const float* bias = (const float*)d_in[4];
  const float* wg   = (const float*)d_in[5];
  const float* wu   = (const float*)d_in[6];
  const float* wd   = (const float*)d_in[7];
  float* out = (float*)d_out;

  char* p = (char*)d_ws;
  auto alloc = [&](size_t bytes) {
    char* r = p;
    p += (bytes + 255) & ~(size_t)255;
    return r;
  };
  int*   counts  = (int*)alloc(NE * 4);
  int*   offs    = (int*)alloc((NE + 1) * 4);
  int*   lists   = (int*)alloc((size_t)NE * T_TOK * 4);
  float* wlist   = (float*)alloc((size_t)NE * T_TOK * 4);
  unsigned short* xb   = (unsigned short*)alloc((size_t)T_TOK * HD * 2);
  unsigned short* abuf = (unsigned short*)alloc((size_t)(T_TOK * NK + 128) * ID * 2);

  hipMemsetAsync(counts, 0, NE * 4, stream);
  router_k<<<T_TOK / 4, 256, 0, stream>>>(x, wr, bias, counts, lists, wlist, xb, out);
  scan_k<<<1, 64, 0, stream>>>(counts, offs);
  gu_k<<<3072, 256, 0, stream>>>(xb, wg, wu, counts, offs, lists, abuf);
  dn_k<<<2048, 256, 0, stream>>>(abuf, wd, counts, offs, lists, wlist, out);
}